// Round 14
// baseline (152.690 us; speedup 1.0000x reference)
//
#include <hip/hip_runtime.h>
#include <hip/hip_bf16.h>
#include <math.h>

// Fused ConvTranspose2d(64->64,k4,s2,p1) + BN + softmax(C) + maxpool2x2 via bf16 MFMA.
//
// R21 == R20 resubmit (R20 bench died to a container/infra failure, no
// counters — same bare-infra signature as R8/R12, both of which passed on
// resubmit). R20 = R19 + persistent 2-tile blocks with cross-tile T14
// pipelining:
//  - 512 blocks (16 phgroups x 32 n), 2/CU -> ALL resident, one dispatch wave.
//    Each block: tiles {P,P+1} then {P+2,P+3} (adjacent -> halo L2-hot).
//  - tile2's 8 halo global_loads issue to REGISTERS right after tile1's
//    softmax, BEFORE the barrier: ~300-600cy latency hides under tile1's
//    entire epilogue (writes/atomics/stores) instead of heading tile2.
//  - per-tile code is R19 verbatim (ks loop w/ wave-private single-buffer
//    wbuf overlaid on red, vmcnt/lgkm discipline, permuted conflict-free
//    epilogue, class0-write + atomics). Barriers 4/tile.
//  - reg peak at overlap: acc 64 + 32 held loads + misc ~116 < 128 @(512,4).
//    No-spill falsifier: WRITE_SIZE stays ~33MB.

typedef __attribute__((ext_vector_type(8))) short short8;
typedef __attribute__((ext_vector_type(4))) float floatx4;
typedef __attribute__((ext_vector_type(2))) unsigned uint2v;

__device__ ushort g_wfrag[4 * 8 * 4 * 64 * 8];  // [class][ks][nt][lane][j], 128 KB
__device__ float g_aff[64];  // ((bias-mean)*A + beta) * log2e

#define L2E 1.44269504088896340736f

__device__ __forceinline__ ushort f2bf(float f) {
  union { float f; unsigned u; } v; v.f = f;
  unsigned r = v.u + 0x7FFF + ((v.u >> 16) & 1);  // RNE
  return (ushort)(r >> 16);
}

// prep: thread = (cin pair, cout). BN scale A and log2(e) folded into weights.
__global__ __launch_bounds__(256) void prep_kernel(
    const float* __restrict__ w, const float* __restrict__ bias,
    const float* __restrict__ gamma, const float* __restrict__ beta,
    const float* __restrict__ mean, const float* __restrict__ var) {
  int t = blockIdx.x * 256 + threadIdx.x;  // 0..2047
  int cin0 = (t >> 6) * 2;                 // even cin
  int cout = t & 63;
  int nt = cout >> 4, b15 = cout & 15;
  int q = (cin0 & 31) >> 3;                // quad within k-step
  int j = cin0 & 7;                        // j within quad (even)
  int ksq = cin0 >> 5;                     // which 32-block within tap
  float Aw = gamma[cout] * rsqrtf(var[cout] + 1e-5f) * L2E;

  const float4* p0 = (const float4*)&w[(cin0 * 64 + cout) * 16];
  const float4* p1 = (const float4*)&w[((cin0 + 1) * 64 + cout) * 16];
  float a[16], b[16];
  {
    float4 f0 = p0[0], f1 = p0[1], f2 = p0[2], f3 = p0[3];
    a[0]=f0.x; a[1]=f0.y; a[2]=f0.z; a[3]=f0.w; a[4]=f1.x; a[5]=f1.y; a[6]=f1.z; a[7]=f1.w;
    a[8]=f2.x; a[9]=f2.y; a[10]=f2.z; a[11]=f2.w; a[12]=f3.x; a[13]=f3.y; a[14]=f3.z; a[15]=f3.w;
    float4 g0 = p1[0], g1 = p1[1], g2 = p1[2], g3 = p1[3];
    b[0]=g0.x; b[1]=g0.y; b[2]=g0.z; b[3]=g0.w; b[4]=g1.x; b[5]=g1.y; b[6]=g1.z; b[7]=g1.w;
    b[8]=g2.x; b[9]=g2.y; b[10]=g2.z; b[11]=g2.w; b[12]=g3.x; b[13]=g3.y; b[14]=g3.z; b[15]=g3.w;
  }
#pragma unroll
  for (int kh = 0; kh < 4; ++kh)
#pragma unroll
    for (int kw = 0; kw < 4; ++kw) {
      int r = (kh & 1) ? 0 : 1;
      int pp = (kw & 1) ? 0 : 1;
      int c = r * 2 + pp;
      int tap = (kh >> 1) * 2 + (kw >> 1);
      int ks = tap * 2 + ksq;
      unsigned u = (unsigned)f2bf(a[kh * 4 + kw] * Aw) |
                   ((unsigned)f2bf(b[kh * 4 + kw] * Aw) << 16);
      *(unsigned*)&g_wfrag[(((c * 8 + ks) * 4 + nt) * 64 + q * 16 + b15) * 8 + j] = u;
    }

  if (t < 64) {
    float A0 = gamma[t] * rsqrtf(var[t] + 1e-5f);
    g_aff[t] = ((bias[t] - mean[t]) * A0 + beta[t]) * L2E;
  }
}

__device__ __forceinline__ unsigned cvtpk(float a, float b) {
  unsigned r;
  asm("v_cvt_pk_bf16_f32 %0, %1, %2" : "=v"(r) : "v"(a), "v"(b));
  return r;
}

template <int CTRL>
__device__ __forceinline__ float dpp_add(float v) {
  unsigned t = (unsigned)__builtin_amdgcn_update_dpp(
      0, (int)__float_as_uint(v), CTRL, 0xF, 0xF, true);
  return v + __uint_as_float(t);
}

// sum across each 16-lane group, result in all lanes, pure-VALU via DPP.
__device__ __forceinline__ float sum16(float v) {
  v = dpp_add<0xB1>(v);   // quad_perm [1,0,3,2]  (xor 1)
  v = dpp_add<0x4E>(v);   // quad_perm [2,3,0,1]  (xor 2)
  v = dpp_add<0x141>(v);  // row_half_mirror      (xor 4)
  v = dpp_add<0x140>(v);  // row_mirror           (xor 8)
  return v;
}

__device__ __forceinline__ float fexp2(float x) {
#if __has_builtin(__builtin_amdgcn_exp2f)
  return __builtin_amdgcn_exp2f(x);
#else
  return exp2f(x);
#endif
}

__device__ __forceinline__ void gload_lds16(const void* g, void* l) {
  __builtin_amdgcn_global_load_lds(
      (const __attribute__((address_space(1))) void*)g,
      (__attribute__((address_space(3))) void*)l, 16, 0, 0);
}

#define COLS 66
#define ROWSTRIDE (COLS * 64)  // 4224 ushorts per halo row

__global__ __launch_bounds__(512, 4) void fused_kernel(const float* __restrict__ x,
                                                       float* __restrict__ out) {
  __shared__ __align__(16) ushort xs[4 * ROWSTRIDE];    // 33792 B halo, swizzled
  __shared__ __align__(16) float red[2 * 64 * 65 + 16];  // 33344 B; first 32KB = wbuf

  ushort* wbuf = (ushort*)red;  // [wave][nt][512] single-buffer, per-wave private

  const int tid  = threadIdx.x;
  // XCD-grouping on the 16 ph-groups: adjacent groups -> same XCD L2
  const int phg  = ((blockIdx.x & 7) << 1) | (blockIdx.x >> 3);  // bijective on [0,16)
  const int P    = phg * 4;  // block covers pooled rows P..P+3 (2 tiles)
  const int n    = blockIdx.y;
  const int wave = tid >> 6;
  const int lane = tid & 63;
  const int b15  = lane & 15;
  const int q    = lane >> 4;
  const int wc   = wave & 1;   // col half (32 cols)
  const int c    = wave >> 1;  // parity class (r,p)
  const int r    = c >> 1, p = c & 1;

  // per-wave private weight staging into the single buffer
#define STAGE_W(ks_)                                                          \
  {                                                                           \
    _Pragma("unroll")                                                         \
    for (int nt_ = 0; nt_ < 4; ++nt_)                                         \
      gload_lds16(&g_wfrag[(((c * 8 + (ks_)) * 4 + nt_) * 64 + lane) * 8],    \
                  &wbuf[(wave * 4 + nt_) * 512]);                             \
  }

  // pack 4 float4 (4 cin-groups of one (row, iw4) cell) into swizzled xs
#define PACK_WRITE(e_, v0_, v1_, v2_, v3_)                                    \
  {                                                                           \
    int iw4_ = (e_)&15, c4_ = ((e_) >> 4) & 15, row_ = (e_) >> 8;             \
    int chunk_ = c4_ >> 1, half4_ = (c4_ & 1) * 4;                            \
    float cc_[4][4] = {{v0_.x, v1_.x, v2_.x, v3_.x}, {v0_.y, v1_.y, v2_.y, v3_.y}, \
                       {v0_.z, v1_.z, v2_.z, v3_.z}, {v0_.w, v1_.w, v2_.w, v3_.w}}; \
    _Pragma("unroll")                                                         \
    for (int ii_ = 0; ii_ < 4; ++ii_) {                                       \
      int col_ = iw4_ * 4 + ii_ + 1;                                          \
      uint2v pk_ = {cvtpk(cc_[ii_][0], cc_[ii_][1]), cvtpk(cc_[ii_][2], cc_[ii_][3])}; \
      *(uint2v*)&xs[(row_ * COLS + col_) * 64 + ((chunk_ ^ (col_ & 7)) * 8) + half4_] = pk_; \
    }                                                                         \
  }

  STAGE_W(0);  // tile1 ks=0: L2 latency hides under halo staging

  // ---- stage tile1 halo rows P-1..P+2 ----
#pragma unroll
  for (int it = 0; it < 2; ++it) {
    int e = tid + it * 512;
    int iw4 = e & 15, c4 = (e >> 4) & 15, row = e >> 8;
    int ih = P - 1 + row;
    float4 v0 = {0.f, 0.f, 0.f, 0.f}, v1 = v0, v2 = v0, v3 = v0;
    if (ih >= 0 && ih < 64) {
      const float* xp = x + ((n * 64 + c4 * 4) * 64 + ih) * 64 + iw4 * 4;
      v0 = *(const float4*)xp;          v1 = *(const float4*)(xp + 4096);
      v2 = *(const float4*)(xp + 8192); v3 = *(const float4*)(xp + 12288);
    }
    PACK_WRITE(e, v0, v1, v2, v3);
  }
  // zero-pad cols 0 and 65 (all 4 rows, all chunks) — persists across tiles
  for (int e = tid; e < 128; e += 512) {
    int c4 = e & 15, side = (e >> 4) & 1, row = e >> 5;
    int col = side ? 65 : 0;
    int chunk = c4 >> 1, half4 = (c4 & 1) * 4;
    ushort4 z; z.x = z.y = z.z = z.w = 0;
    *(ushort4*)&xs[(row * COLS + col) * 64 + ((chunk ^ (col & 7)) * 8) + half4] = z;
  }

  // BN bias (already * log2e) -> MFMA C-in
  float Dc[4];
#pragma unroll
  for (int nt = 0; nt < 4; ++nt) Dc[nt] = g_aff[nt * 16 + b15];

  // a-frag base addresses A2[b][par] (mt 0, prow 0, a=1 row); mt (+1024 ushort),
  // prow/a (+ROWSTRIDE) are compile-time immediates on the ds_read.
  int A2[2][2];
#pragma unroll
  for (int b = 0; b < 2; ++b) {
    int col = wc * 32 + b15 + (b ? p - 1 : p) + 1;  // 0..65 (mt=0)
#pragma unroll
    for (int par = 0; par < 2; ++par)
      A2[b][par] = r * ROWSTRIDE + col * 64 + (((par * 4 + q) ^ (col & 7)) * 8);
  }

  __syncthreads();  // halo complete; tile1 ks=0 stage drained

#pragma unroll
  for (int t = 0; t < 2; ++t) {
    if (t == 1) STAGE_W(0);  // tile2 ks=0 (wbuf free after the pre-loop barrier)

    floatx4 acc[16];  // [prow*8 + mt*4 + nt], C-in = BN bias
#pragma unroll
    for (int i = 0; i < 16; ++i) {
      float d = Dc[i & 3];
      acc[i] = (floatx4){d, d, d, d};
    }

#pragma unroll
    for (int ks = 0; ks < 8; ++ks) {
      asm volatile("s_waitcnt vmcnt(0)" ::: "memory");  // own stage complete
      short8 bf[4];
#pragma unroll
      for (int nt = 0; nt < 4; ++nt)
        bf[nt] = *(const short8*)&wbuf[(wave * 4 + nt) * 512 + lane * 8];
      const int b_ = (ks >> 1) & 1, par_ = ks & 1;
      const int ro = (ks >> 2) ? 0 : ROWSTRIDE;  // (1-a)*RS
      const int base = A2[b_][par_] + ro;
      short8 af00 = *(const short8*)&xs[base];                     // prow0 mt0
      short8 af01 = *(const short8*)&xs[base + 1024];              // prow0 mt1
      short8 af10 = *(const short8*)&xs[base + ROWSTRIDE];         // prow1 mt0
      short8 af11 = *(const short8*)&xs[base + ROWSTRIDE + 1024];  // prow1 mt1
      asm volatile("s_waitcnt lgkmcnt(0)" ::: "memory");  // reads retired
      if (ks < 7) STAGE_W(ks + 1);  // in flight across the MFMAs
#pragma unroll
      for (int nt = 0; nt < 4; ++nt) {
        acc[nt]      = __builtin_amdgcn_mfma_f32_16x16x32_bf16(af00, bf[nt], acc[nt], 0, 0, 0);
        acc[4 + nt]  = __builtin_amdgcn_mfma_f32_16x16x32_bf16(af01, bf[nt], acc[4 + nt], 0, 0, 0);
        acc[8 + nt]  = __builtin_amdgcn_mfma_f32_16x16x32_bf16(af10, bf[nt], acc[8 + nt], 0, 0, 0);
        acc[12 + nt] = __builtin_amdgcn_mfma_f32_16x16x32_bf16(af11, bf[nt], acc[12 + nt], 0, 0, 0);
      }
    }

    // ---- softmax in registers ----
#pragma unroll
    for (int prow = 0; prow < 2; ++prow)
#pragma unroll
      for (int mt = 0; mt < 2; ++mt) {
        float sm[4] = {0.f, 0.f, 0.f, 0.f};
#pragma unroll
        for (int nt = 0; nt < 4; ++nt)
#pragma unroll
          for (int reg = 0; reg < 4; ++reg) {
            float e = fexp2(acc[prow * 8 + mt * 4 + nt][reg]);
            acc[prow * 8 + mt * 4 + nt][reg] = e;
            sm[reg] += e;
          }
#pragma unroll
        for (int reg = 0; reg < 4; ++reg)
          sm[reg] = __builtin_amdgcn_rcpf(sum16(sm[reg]));
#pragma unroll
        for (int nt = 0; nt < 4; ++nt)
#pragma unroll
          for (int reg = 0; reg < 4; ++reg)
            acc[prow * 8 + mt * 4 + nt][reg] *= sm[reg];  // final probabilities
      }

    // T14: issue tile2's halo loads to regs BEFORE the barrier — latency
    // hides under tile1's entire epilogue.
    float4 t2v[2][4];
    if (t == 0) {
#pragma unroll
      for (int it = 0; it < 2; ++it) {
        int e = tid + it * 512;
        int iw4 = e & 15, c4 = (e >> 4) & 15, row = e >> 8;
        int ih = P + 1 + row;  // tile2 halo rows P+1..P+4
        float4 z = {0.f, 0.f, 0.f, 0.f};
        t2v[it][0] = z; t2v[it][1] = z; t2v[it][2] = z; t2v[it][3] = z;
        if (ih < 64) {
          const float* xp = x + ((n * 64 + c4 * 4) * 64 + ih) * 64 + iw4 * 4;
          t2v[it][0] = *(const float4*)xp;          t2v[it][1] = *(const float4*)(xp + 4096);
          t2v[it][2] = *(const float4*)(xp + 8192); t2v[it][3] = *(const float4*)(xp + 12288);
        }
      }
    }

    __syncthreads();  // all waves done reading xs/wbuf for this tile

    if (t == 0) {  // write tile2 halo into xs (overlaps epilogue below)
#pragma unroll
      for (int it = 0; it < 2; ++it) {
        int e = tid + it * 512;
        PACK_WRITE(e, t2v[it][0], t2v[it][1], t2v[it][2], t2v[it][3]);
      }
    }

    // ---- cross-class maxpool, conflict-free permuted layout ----
    if (c == 0) {
#pragma unroll
      for (int prow = 0; prow < 2; ++prow)
#pragma unroll
        for (int mt = 0; mt < 2; ++mt)
#pragma unroll
          for (int nt = 0; nt < 4; ++nt) {
            int idx = (prow * 64 + nt * 16 + b15) * 65 + wc * 32 + q * 8 + mt * 4;
#pragma unroll
            for (int reg = 0; reg < 4; ++reg)
              red[idx + reg] = acc[prow * 8 + mt * 4 + nt][reg];
          }
    }
    __syncthreads();  // class-0 baseline visible
    if (c != 0) {
#pragma unroll
      for (int prow = 0; prow < 2; ++prow)
#pragma unroll
        for (int mt = 0; mt < 2; ++mt)
#pragma unroll
          for (int nt = 0; nt < 4; ++nt) {
            int idx = (prow * 64 + nt * 16 + b15) * 65 + wc * 32 + q * 8 + mt * 4;
#pragma unroll
            for (int reg = 0; reg < 4; ++reg)
              __hip_atomic_fetch_max((unsigned*)&red[idx + reg],
                                     __float_as_uint(acc[prow * 8 + mt * 4 + nt][reg]),
                                     __ATOMIC_RELAXED, __HIP_MEMORY_SCOPE_WORKGROUP);
          }
    }
    __syncthreads();  // pooled max complete

    // ---- coalesced stores (invert the column permutation in index math) ----
    const int ph0 = P + 2 * t;
    for (int e = tid; e < 4096; e += 512) {
      int pw2  = e & 31;
      int cout = (e >> 5) & 63;
      int rl   = e >> 11;
      int pw   = pw2 * 2;
      int Lh   = pw & 31;
      int phys = ((pw >> 5) << 5) | (((Lh >> 2) & 3) << 3) | (((Lh >> 4) & 1) << 2) | (Lh & 3);
      int base = (rl * 64 + cout) * 65 + phys;
      float2 val = {red[base], red[base + 1]};
      *(float2*)&out[((n * 64 + cout) * 64 + (ph0 + rl)) * 64 + pw] = val;
    }

    if (t == 0) __syncthreads();  // red reads retired before tile2's wbuf DMA
  }
}

extern "C" void kernel_launch(void* const* d_in, const int* in_sizes, int n_in,
                              void* d_out, int out_size, void* d_ws, size_t ws_size,
                              hipStream_t stream) {
  const float* x     = (const float*)d_in[0];
  const float* w     = (const float*)d_in[1];
  const float* bias  = (const float*)d_in[2];
  const float* gamma = (const float*)d_in[3];
  const float* beta  = (const float*)d_in[4];
  const float* mean  = (const float*)d_in[5];
  const float* var   = (const float*)d_in[6];
  float* out = (float*)d_out;

  prep_kernel<<<8, 256, 0, stream>>>(w, bias, gamma, beta, mean, var);
  dim3 grid(16, 32);  // (4-row ph-groups [XCD-swizzled], n) — 512 blocks, all resident
  fused_kernel<<<grid, 512, 0, stream>>>(x, out);
}

// Round 15
// 146.550 us; speedup vs baseline: 1.0419x; 1.0419x over previous
//
#include <hip/hip_runtime.h>
#include <hip/hip_bf16.h>
#include <math.h>

// Fused ConvTranspose2d(64->64,k4,s2,p1) + BN + softmax(C) + maxpool2x2 via bf16 MFMA.
//
// R22 = R19 + persistent 2-tile blocks, NO register prefetch (R21's held
// t2v[32 float regs] + acc[64 AGPR] blew the 128-reg cap -> 130MB scratch).
//  - 512 blocks (16 phgroups x 32 n), 2/CU -> ALL resident, one dispatch wave.
//    Each block: tiles {P,P+1} then {P+2,P+3} (adjacent -> halo L2-hot).
//  - tile2 halo staging (load -> cvtpk -> xs write) placed right AFTER
//    tile1's post-loop barrier, interleaved with the epilogue: loads issue
//    before the red-writes/atomics/stores, latency hides under ~2K cy of
//    epilogue work, nothing held across a phase boundary.
//  - per-tile code is R19 verbatim (ks loop w/ wave-private single-buffer
//    wbuf overlaid on red, vmcnt/lgkm discipline, permuted conflict-free
//    epilogue, class0-write + atomics).
//  - hazards: tile2 xs writes sit between barrier(2) (tile1 xs reads
//    retired) and barrier(3) (visibility for tile2 ks); tile2's STAGE_W(0)
//    DMA into wbuf(=red) happens after the end-of-tile barrier that retires
//    the store-loop's red reads.
//  - register peak == R19 (~64 VGPR + 64 AGPR). No-spill falsifiers:
//    WRITE_SIZE ~33MB, FETCH ~20MB.

typedef __attribute__((ext_vector_type(8))) short short8;
typedef __attribute__((ext_vector_type(4))) float floatx4;
typedef __attribute__((ext_vector_type(2))) unsigned uint2v;

__device__ ushort g_wfrag[4 * 8 * 4 * 64 * 8];  // [class][ks][nt][lane][j], 128 KB
__device__ float g_aff[64];  // ((bias-mean)*A + beta) * log2e

#define L2E 1.44269504088896340736f

__device__ __forceinline__ ushort f2bf(float f) {
  union { float f; unsigned u; } v; v.f = f;
  unsigned r = v.u + 0x7FFF + ((v.u >> 16) & 1);  // RNE
  return (ushort)(r >> 16);
}

// prep: thread = (cin pair, cout). BN scale A and log2(e) folded into weights.
__global__ __launch_bounds__(256) void prep_kernel(
    const float* __restrict__ w, const float* __restrict__ bias,
    const float* __restrict__ gamma, const float* __restrict__ beta,
    const float* __restrict__ mean, const float* __restrict__ var) {
  int t = blockIdx.x * 256 + threadIdx.x;  // 0..2047
  int cin0 = (t >> 6) * 2;                 // even cin
  int cout = t & 63;
  int nt = cout >> 4, b15 = cout & 15;
  int q = (cin0 & 31) >> 3;                // quad within k-step
  int j = cin0 & 7;                        // j within quad (even)
  int ksq = cin0 >> 5;                     // which 32-block within tap
  float Aw = gamma[cout] * rsqrtf(var[cout] + 1e-5f) * L2E;

  const float4* p0 = (const float4*)&w[(cin0 * 64 + cout) * 16];
  const float4* p1 = (const float4*)&w[((cin0 + 1) * 64 + cout) * 16];
  float a[16], b[16];
  {
    float4 f0 = p0[0], f1 = p0[1], f2 = p0[2], f3 = p0[3];
    a[0]=f0.x; a[1]=f0.y; a[2]=f0.z; a[3]=f0.w; a[4]=f1.x; a[5]=f1.y; a[6]=f1.z; a[7]=f1.w;
    a[8]=f2.x; a[9]=f2.y; a[10]=f2.z; a[11]=f2.w; a[12]=f3.x; a[13]=f3.y; a[14]=f3.z; a[15]=f3.w;
    float4 g0 = p1[0], g1 = p1[1], g2 = p1[2], g3 = p1[3];
    b[0]=g0.x; b[1]=g0.y; b[2]=g0.z; b[3]=g0.w; b[4]=g1.x; b[5]=g1.y; b[6]=g1.z; b[7]=g1.w;
    b[8]=g2.x; b[9]=g2.y; b[10]=g2.z; b[11]=g2.w; b[12]=g3.x; b[13]=g3.y; b[14]=g3.z; b[15]=g3.w;
  }
#pragma unroll
  for (int kh = 0; kh < 4; ++kh)
#pragma unroll
    for (int kw = 0; kw < 4; ++kw) {
      int r = (kh & 1) ? 0 : 1;
      int pp = (kw & 1) ? 0 : 1;
      int c = r * 2 + pp;
      int tap = (kh >> 1) * 2 + (kw >> 1);
      int ks = tap * 2 + ksq;
      unsigned u = (unsigned)f2bf(a[kh * 4 + kw] * Aw) |
                   ((unsigned)f2bf(b[kh * 4 + kw] * Aw) << 16);
      *(unsigned*)&g_wfrag[(((c * 8 + ks) * 4 + nt) * 64 + q * 16 + b15) * 8 + j] = u;
    }

  if (t < 64) {
    float A0 = gamma[t] * rsqrtf(var[t] + 1e-5f);
    g_aff[t] = ((bias[t] - mean[t]) * A0 + beta[t]) * L2E;
  }
}

__device__ __forceinline__ unsigned cvtpk(float a, float b) {
  unsigned r;
  asm("v_cvt_pk_bf16_f32 %0, %1, %2" : "=v"(r) : "v"(a), "v"(b));
  return r;
}

template <int CTRL>
__device__ __forceinline__ float dpp_add(float v) {
  unsigned t = (unsigned)__builtin_amdgcn_update_dpp(
      0, (int)__float_as_uint(v), CTRL, 0xF, 0xF, true);
  return v + __uint_as_float(t);
}

// sum across each 16-lane group, result in all lanes, pure-VALU via DPP.
__device__ __forceinline__ float sum16(float v) {
  v = dpp_add<0xB1>(v);   // quad_perm [1,0,3,2]  (xor 1)
  v = dpp_add<0x4E>(v);   // quad_perm [2,3,0,1]  (xor 2)
  v = dpp_add<0x141>(v);  // row_half_mirror      (xor 4)
  v = dpp_add<0x140>(v);  // row_mirror           (xor 8)
  return v;
}

__device__ __forceinline__ float fexp2(float x) {
#if __has_builtin(__builtin_amdgcn_exp2f)
  return __builtin_amdgcn_exp2f(x);
#else
  return exp2f(x);
#endif
}

__device__ __forceinline__ void gload_lds16(const void* g, void* l) {
  __builtin_amdgcn_global_load_lds(
      (const __attribute__((address_space(1))) void*)g,
      (__attribute__((address_space(3))) void*)l, 16, 0, 0);
}

#define COLS 66
#define ROWSTRIDE (COLS * 64)  // 4224 ushorts per halo row

__global__ __launch_bounds__(512, 4) void fused_kernel(const float* __restrict__ x,
                                                       float* __restrict__ out) {
  __shared__ __align__(16) ushort xs[4 * ROWSTRIDE];    // 33792 B halo, swizzled
  __shared__ __align__(16) float red[2 * 64 * 65 + 16];  // 33344 B; first 32KB = wbuf

  ushort* wbuf = (ushort*)red;  // [wave][nt][512] single-buffer, per-wave private

  const int tid  = threadIdx.x;
  // XCD-grouping on the 16 ph-groups: adjacent groups -> same XCD L2
  const int phg  = ((blockIdx.x & 7) << 1) | (blockIdx.x >> 3);  // bijective on [0,16)
  const int P    = phg * 4;  // block covers pooled rows P..P+3 (2 tiles)
  const int n    = blockIdx.y;
  const int wave = tid >> 6;
  const int lane = tid & 63;
  const int b15  = lane & 15;
  const int q    = lane >> 4;
  const int wc   = wave & 1;   // col half (32 cols)
  const int c    = wave >> 1;  // parity class (r,p)
  const int r    = c >> 1, p = c & 1;

  // per-wave private weight staging into the single buffer
#define STAGE_W(ks_)                                                          \
  {                                                                           \
    _Pragma("unroll")                                                         \
    for (int nt_ = 0; nt_ < 4; ++nt_)                                         \
      gload_lds16(&g_wfrag[(((c * 8 + (ks_)) * 4 + nt_) * 64 + lane) * 8],    \
                  &wbuf[(wave * 4 + nt_) * 512]);                             \
  }

  // load one (row, iw4, 4xcin-group) cell from x at input row ih_ and pack
  // it into the swizzled xs halo slot for halo-row row_
#define STAGE_X_CELL(e_, ih_)                                                 \
  {                                                                           \
    int iw4_ = (e_)&15, c4_ = ((e_) >> 4) & 15, row_ = (e_) >> 8;             \
    float4 v0_ = {0.f, 0.f, 0.f, 0.f}, v1_ = v0_, v2_ = v0_, v3_ = v0_;       \
    if ((unsigned)(ih_) < 64u) {                                              \
      const float* xp_ = x + ((n * 64 + c4_ * 4) * 64 + (ih_)) * 64 + iw4_ * 4; \
      v0_ = *(const float4*)xp_;          v1_ = *(const float4*)(xp_ + 4096); \
      v2_ = *(const float4*)(xp_ + 8192); v3_ = *(const float4*)(xp_ + 12288); \
    }                                                                         \
    int chunk_ = c4_ >> 1, half4_ = (c4_ & 1) * 4;                            \
    float cc_[4][4] = {{v0_.x, v1_.x, v2_.x, v3_.x}, {v0_.y, v1_.y, v2_.y, v3_.y}, \
                       {v0_.z, v1_.z, v2_.z, v3_.z}, {v0_.w, v1_.w, v2_.w, v3_.w}}; \
    _Pragma("unroll")                                                         \
    for (int ii_ = 0; ii_ < 4; ++ii_) {                                       \
      int col_ = iw4_ * 4 + ii_ + 1;                                          \
      uint2v pk_ = {cvtpk(cc_[ii_][0], cc_[ii_][1]), cvtpk(cc_[ii_][2], cc_[ii_][3])}; \
      *(uint2v*)&xs[(row_ * COLS + col_) * 64 + ((chunk_ ^ (col_ & 7)) * 8) + half4_] = pk_; \
    }                                                                         \
  }

  STAGE_W(0);  // tile1 ks=0: L2 latency hides under halo staging

  // ---- stage tile1 halo rows P-1..P+2 ----
#pragma unroll
  for (int it = 0; it < 2; ++it) {
    int e = tid + it * 512;
    STAGE_X_CELL(e, P - 1 + (e >> 8));
  }
  // zero-pad cols 0 and 65 (all 4 rows, all chunks) — persists across tiles
  for (int e = tid; e < 128; e += 512) {
    int c4 = e & 15, side = (e >> 4) & 1, row = e >> 5;
    int col = side ? 65 : 0;
    int chunk = c4 >> 1, half4 = (c4 & 1) * 4;
    ushort4 z; z.x = z.y = z.z = z.w = 0;
    *(ushort4*)&xs[(row * COLS + col) * 64 + ((chunk ^ (col & 7)) * 8) + half4] = z;
  }

  // BN bias (already * log2e) -> MFMA C-in
  float Dc[4];
#pragma unroll
  for (int nt = 0; nt < 4; ++nt) Dc[nt] = g_aff[nt * 16 + b15];

  // a-frag base addresses A2[b][par] (mt 0, prow 0, a=1 row); mt (+1024 ushort),
  // prow/a (+ROWSTRIDE) are compile-time immediates on the ds_read.
  int A2[2][2];
#pragma unroll
  for (int b = 0; b < 2; ++b) {
    int col = wc * 32 + b15 + (b ? p - 1 : p) + 1;  // 0..65 (mt=0)
#pragma unroll
    for (int par = 0; par < 2; ++par)
      A2[b][par] = r * ROWSTRIDE + col * 64 + (((par * 4 + q) ^ (col & 7)) * 8);
  }

  __syncthreads();  // (1) halo complete; tile1 ks=0 stage drained

#pragma unroll
  for (int t = 0; t < 2; ++t) {
    if (t == 1) STAGE_W(0);  // tile2 ks=0 (wbuf free after the end-of-tile barrier)

    floatx4 acc[16];  // [prow*8 + mt*4 + nt], C-in = BN bias
#pragma unroll
    for (int i = 0; i < 16; ++i) {
      float d = Dc[i & 3];
      acc[i] = (floatx4){d, d, d, d};
    }

#pragma unroll
    for (int ks = 0; ks < 8; ++ks) {
      asm volatile("s_waitcnt vmcnt(0)" ::: "memory");  // own stage complete
      short8 bf[4];
#pragma unroll
      for (int nt = 0; nt < 4; ++nt)
        bf[nt] = *(const short8*)&wbuf[(wave * 4 + nt) * 512 + lane * 8];
      const int b_ = (ks >> 1) & 1, par_ = ks & 1;
      const int ro = (ks >> 2) ? 0 : ROWSTRIDE;  // (1-a)*RS
      const int base = A2[b_][par_] + ro;
      short8 af00 = *(const short8*)&xs[base];                     // prow0 mt0
      short8 af01 = *(const short8*)&xs[base + 1024];              // prow0 mt1
      short8 af10 = *(const short8*)&xs[base + ROWSTRIDE];         // prow1 mt0
      short8 af11 = *(const short8*)&xs[base + ROWSTRIDE + 1024];  // prow1 mt1
      asm volatile("s_waitcnt lgkmcnt(0)" ::: "memory");  // reads retired
      if (ks < 7) STAGE_W(ks + 1);  // in flight across the MFMAs
#pragma unroll
      for (int nt = 0; nt < 4; ++nt) {
        acc[nt]      = __builtin_amdgcn_mfma_f32_16x16x32_bf16(af00, bf[nt], acc[nt], 0, 0, 0);
        acc[4 + nt]  = __builtin_amdgcn_mfma_f32_16x16x32_bf16(af01, bf[nt], acc[4 + nt], 0, 0, 0);
        acc[8 + nt]  = __builtin_amdgcn_mfma_f32_16x16x32_bf16(af10, bf[nt], acc[8 + nt], 0, 0, 0);
        acc[12 + nt] = __builtin_amdgcn_mfma_f32_16x16x32_bf16(af11, bf[nt], acc[12 + nt], 0, 0, 0);
      }
    }

    // ---- softmax in registers ----
#pragma unroll
    for (int prow = 0; prow < 2; ++prow)
#pragma unroll
      for (int mt = 0; mt < 2; ++mt) {
        float sm[4] = {0.f, 0.f, 0.f, 0.f};
#pragma unroll
        for (int nt = 0; nt < 4; ++nt)
#pragma unroll
          for (int reg = 0; reg < 4; ++reg) {
            float e = fexp2(acc[prow * 8 + mt * 4 + nt][reg]);
            acc[prow * 8 + mt * 4 + nt][reg] = e;
            sm[reg] += e;
          }
#pragma unroll
        for (int reg = 0; reg < 4; ++reg)
          sm[reg] = __builtin_amdgcn_rcpf(sum16(sm[reg]));
#pragma unroll
        for (int nt = 0; nt < 4; ++nt)
#pragma unroll
          for (int reg = 0; reg < 4; ++reg)
            acc[prow * 8 + mt * 4 + nt][reg] *= sm[reg];  // final probabilities
      }

    __syncthreads();  // (2) all waves done reading xs/wbuf for this tile

    // tile2 halo staging: loads issue here, latency hides under the epilogue
    // below (red writes/atomics/stores touch red only, disjoint from xs)
    if (t == 0) {
#pragma unroll
      for (int it = 0; it < 2; ++it) {
        int e = tid + it * 512;
        STAGE_X_CELL(e, P + 1 + (e >> 8));  // tile2 halo rows P+1..P+4
      }
    }

    // ---- cross-class maxpool, conflict-free permuted layout ----
    if (c == 0) {
#pragma unroll
      for (int prow = 0; prow < 2; ++prow)
#pragma unroll
        for (int mt = 0; mt < 2; ++mt)
#pragma unroll
          for (int nt = 0; nt < 4; ++nt) {
            int idx = (prow * 64 + nt * 16 + b15) * 65 + wc * 32 + q * 8 + mt * 4;
#pragma unroll
            for (int reg = 0; reg < 4; ++reg)
              red[idx + reg] = acc[prow * 8 + mt * 4 + nt][reg];
          }
    }
    __syncthreads();  // (3) class-0 baseline + tile2 xs writes visible
    if (c != 0) {
#pragma unroll
      for (int prow = 0; prow < 2; ++prow)
#pragma unroll
        for (int mt = 0; mt < 2; ++mt)
#pragma unroll
          for (int nt = 0; nt < 4; ++nt) {
            int idx = (prow * 64 + nt * 16 + b15) * 65 + wc * 32 + q * 8 + mt * 4;
#pragma unroll
            for (int reg = 0; reg < 4; ++reg)
              __hip_atomic_fetch_max((unsigned*)&red[idx + reg],
                                     __float_as_uint(acc[prow * 8 + mt * 4 + nt][reg]),
                                     __ATOMIC_RELAXED, __HIP_MEMORY_SCOPE_WORKGROUP);
          }
    }
    __syncthreads();  // (4) pooled max complete

    // ---- coalesced stores (invert the column permutation in index math) ----
    const int ph0 = P + 2 * t;
    for (int e = tid; e < 4096; e += 512) {
      int pw2  = e & 31;
      int cout = (e >> 5) & 63;
      int rl   = e >> 11;
      int pw   = pw2 * 2;
      int Lh   = pw & 31;
      int phys = ((pw >> 5) << 5) | (((Lh >> 2) & 3) << 3) | (((Lh >> 4) & 1) << 2) | (Lh & 3);
      int base = (rl * 64 + cout) * 65 + phys;
      float2 val = {red[base], red[base + 1]};
      *(float2*)&out[((n * 64 + cout) * 64 + (ph0 + rl)) * 64 + pw] = val;
    }

    if (t == 0) __syncthreads();  // red reads retired before tile2's wbuf DMA
  }
}

extern "C" void kernel_launch(void* const* d_in, const int* in_sizes, int n_in,
                              void* d_out, int out_size, void* d_ws, size_t ws_size,
                              hipStream_t stream) {
  const float* x     = (const float*)d_in[0];
  const float* w     = (const float*)d_in[1];
  const float* bias  = (const float*)d_in[2];
  const float* gamma = (const float*)d_in[3];
  const float* beta  = (const float*)d_in[4];
  const float* mean  = (const float*)d_in[5];
  const float* var   = (const float*)d_in[6];
  float* out = (float*)d_out;

  prep_kernel<<<8, 256, 0, stream>>>(w, bias, gamma, beta, mean, var);
  dim3 grid(16, 32);  // (4-row ph-groups [XCD-swizzled], n) — 512 blocks, all resident
  fused_kernel<<<grid, 512, 0, stream>>>(x, out);
}

// Round 16
// 112.096 us; speedup vs baseline: 1.3621x; 1.3074x over previous
//
#include <hip/hip_runtime.h>
#include <hip/hip_bf16.h>
#include <math.h>

// Fused ConvTranspose2d(64->64,k4,s2,p1) + BN + softmax(C) + maxpool2x2 via bf16 MFMA.
//
// R23 == R15 resubmit (best measured: 112.58us total, fused ~38us).
// Session conclusion: 5 structural variants (R13/14/15/18/19) plateau at
// fused 38-43us; all cross-tile-overlap attempts (R20/21/22) spilled
// (acc[16] = 64 AGPR leaves no room for cross-phase state at 4 waves/SIMD);
// occupancy is LDS-capped at 16 waves/CU (2-prow halo 33.8KB + 32KB weight
// buffer; 3 blocks/CU needs <=53.3KB, reachable only via register weights
// [spills] or 1-prow [slower, R13]). Residual conflict counter (3072
// cy/tile/block) is inherent wave64 ds_read_b128 aliasing, not fixable.
//
// R15 structure:
//  - weights staged to LDS via global_load_lds (16B/lane, fire-and-forget),
//    double-buffered wbuf[2][16seg][1KB]; wave (c,wc) stages its class's
//    nt=2wc,2wc+1 for ks+1 at top of iteration ks; one __syncthreads per ks.
//    Each weight byte read from L2 once per block (wave-pair sharing).
//  - 2 pooled rows per block (grid 32x32, 4-row halo): acc[16] fits since
//    bf regs freed by LDS weights -> no spill at (512,4).
//  - red[2][64][65] overlaid on xs (dead after last ks barrier):
//    LDS = 33792(xs) + 32768(wbuf) = 66560 -> 2 blocks/CU.
//  - class-per-wave, pitch-65 ds_max_u32 pooling, XCD-grouping swizzle,
//    BN bias as MFMA C-in, log2e folded into weights, padded 66-col halo,
//    DPP 16-lane softmax reduce, v_cvt_pk_bf16_f32 staging.

typedef __attribute__((ext_vector_type(8))) short short8;
typedef __attribute__((ext_vector_type(4))) float floatx4;
typedef __attribute__((ext_vector_type(2))) unsigned uint2v;

__device__ ushort g_wfrag[4 * 8 * 4 * 64 * 8];  // [class][ks][nt][lane][j], 128 KB
__device__ float g_aff[64];  // ((bias-mean)*A + beta) * log2e

#define L2E 1.44269504088896340736f

__device__ __forceinline__ ushort f2bf(float f) {
  union { float f; unsigned u; } v; v.f = f;
  unsigned r = v.u + 0x7FFF + ((v.u >> 16) & 1);  // RNE
  return (ushort)(r >> 16);
}

// prep: thread = (cin pair, cout). BN scale A and log2(e) folded into weights.
__global__ __launch_bounds__(256) void prep_kernel(
    const float* __restrict__ w, const float* __restrict__ bias,
    const float* __restrict__ gamma, const float* __restrict__ beta,
    const float* __restrict__ mean, const float* __restrict__ var) {
  int t = blockIdx.x * 256 + threadIdx.x;  // 0..2047
  int cin0 = (t >> 6) * 2;                 // even cin
  int cout = t & 63;
  int nt = cout >> 4, b15 = cout & 15;
  int q = (cin0 & 31) >> 3;                // quad within k-step
  int j = cin0 & 7;                        // j within quad (even)
  int ksq = cin0 >> 5;                     // which 32-block within tap
  float Aw = gamma[cout] * rsqrtf(var[cout] + 1e-5f) * L2E;

  const float4* p0 = (const float4*)&w[(cin0 * 64 + cout) * 16];
  const float4* p1 = (const float4*)&w[((cin0 + 1) * 64 + cout) * 16];
  float a[16], b[16];
  {
    float4 f0 = p0[0], f1 = p0[1], f2 = p0[2], f3 = p0[3];
    a[0]=f0.x; a[1]=f0.y; a[2]=f0.z; a[3]=f0.w; a[4]=f1.x; a[5]=f1.y; a[6]=f1.z; a[7]=f1.w;
    a[8]=f2.x; a[9]=f2.y; a[10]=f2.z; a[11]=f2.w; a[12]=f3.x; a[13]=f3.y; a[14]=f3.z; a[15]=f3.w;
    float4 g0 = p1[0], g1 = p1[1], g2 = p1[2], g3 = p1[3];
    b[0]=g0.x; b[1]=g0.y; b[2]=g0.z; b[3]=g0.w; b[4]=g1.x; b[5]=g1.y; b[6]=g1.z; b[7]=g1.w;
    b[8]=g2.x; b[9]=g2.y; b[10]=g2.z; b[11]=g2.w; b[12]=g3.x; b[13]=g3.y; b[14]=g3.z; b[15]=g3.w;
  }
#pragma unroll
  for (int kh = 0; kh < 4; ++kh)
#pragma unroll
    for (int kw = 0; kw < 4; ++kw) {
      int r = (kh & 1) ? 0 : 1;
      int pp = (kw & 1) ? 0 : 1;
      int c = r * 2 + pp;
      int tap = (kh >> 1) * 2 + (kw >> 1);
      int ks = tap * 2 + ksq;
      unsigned u = (unsigned)f2bf(a[kh * 4 + kw] * Aw) |
                   ((unsigned)f2bf(b[kh * 4 + kw] * Aw) << 16);
      *(unsigned*)&g_wfrag[(((c * 8 + ks) * 4 + nt) * 64 + q * 16 + b15) * 8 + j] = u;
    }

  if (t < 64) {
    float A0 = gamma[t] * rsqrtf(var[t] + 1e-5f);
    g_aff[t] = ((bias[t] - mean[t]) * A0 + beta[t]) * L2E;
  }
}

__device__ __forceinline__ unsigned cvtpk(float a, float b) {
  unsigned r;
  asm("v_cvt_pk_bf16_f32 %0, %1, %2" : "=v"(r) : "v"(a), "v"(b));
  return r;
}

template <int CTRL>
__device__ __forceinline__ float dpp_add(float v) {
  unsigned t = (unsigned)__builtin_amdgcn_update_dpp(
      0, (int)__float_as_uint(v), CTRL, 0xF, 0xF, true);
  return v + __uint_as_float(t);
}

// sum across each 16-lane group, result in all lanes, pure-VALU via DPP.
__device__ __forceinline__ float sum16(float v) {
  v = dpp_add<0xB1>(v);   // quad_perm [1,0,3,2]  (xor 1)
  v = dpp_add<0x4E>(v);   // quad_perm [2,3,0,1]  (xor 2)
  v = dpp_add<0x141>(v);  // row_half_mirror      (xor 4)
  v = dpp_add<0x140>(v);  // row_mirror           (xor 8)
  return v;
}

__device__ __forceinline__ float fexp2(float x) {
#if __has_builtin(__builtin_amdgcn_exp2f)
  return __builtin_amdgcn_exp2f(x);
#else
  return exp2f(x);
#endif
}

__device__ __forceinline__ void gload_lds16(const void* g, void* l) {
  __builtin_amdgcn_global_load_lds(
      (const __attribute__((address_space(1))) void*)g,
      (__attribute__((address_space(3))) void*)l, 16, 0, 0);
}

#define COLS 66
#define ROWSTRIDE (COLS * 64)  // 4224 ushorts per halo row

__global__ __launch_bounds__(512, 4) void fused_kernel(const float* __restrict__ x,
                                                       float* __restrict__ out) {
  __shared__ __align__(16) ushort xs[4 * ROWSTRIDE];    // 33792 B halo; reused as red
  __shared__ __align__(16) ushort wbuf[2 * 16 * 512];   // 32768 B weight dbuf

  const int tid  = threadIdx.x;
  // XCD-grouping: consecutive ph-pairs (sharing halo rows) -> same XCD L2
  const int swz  = ((blockIdx.x & 7) << 2) | (blockIdx.x >> 3);  // bijective on [0,32)
  const int ph0  = swz * 2;
  const int n    = blockIdx.y;
  const int wave = tid >> 6;
  const int lane = tid & 63;
  const int b15  = lane & 15;
  const int q    = lane >> 4;
  const int wc   = wave & 1;   // col half (32 cols)
  const int c    = wave >> 1;  // parity class (r,p)
  const int r    = c >> 1, p = c & 1;

  // stage wbuf[0] (ks=0) first: L2 latency hides under the halo staging
#define STAGE_W(buf_, ksrc_)                                                      \
  {                                                                               \
    const int nt0_ = 2 * wc;                                                      \
    gload_lds16(&g_wfrag[(((c * 8 + (ksrc_)) * 4 + nt0_) * 64 + lane) * 8],       \
                &wbuf[((buf_) * 16 + c * 4 + nt0_) * 512]);                       \
    gload_lds16(&g_wfrag[(((c * 8 + (ksrc_)) * 4 + nt0_ + 1) * 64 + lane) * 8],   \
                &wbuf[((buf_) * 16 + c * 4 + nt0_ + 1) * 512]);                   \
  }
  STAGE_W(0, 0);

  // ---- stage x halo rows ph0-1..ph0+2, swizzled [row][col+1][chunk^(col&7)] ----
  for (int e = tid; e < 1024; e += 512) {
    int iw4 = e & 15;          // group of 4 iw
    int c4  = (e >> 4) & 15;   // group of 4 cin
    int row = e >> 8;          // 0..3
    int ih  = ph0 - 1 + row;
    float4 v0 = {0.f, 0.f, 0.f, 0.f}, v1 = v0, v2 = v0, v3 = v0;
    if (ih >= 0 && ih < 64) {
      const float* xp = x + ((n * 64 + c4 * 4) * 64 + ih) * 64 + iw4 * 4;
      v0 = *(const float4*)xp;          v1 = *(const float4*)(xp + 4096);
      v2 = *(const float4*)(xp + 8192); v3 = *(const float4*)(xp + 12288);
    }
    int chunk = c4 >> 1, half4 = (c4 & 1) * 4;
    float cc[4][4] = {{v0.x, v1.x, v2.x, v3.x}, {v0.y, v1.y, v2.y, v3.y},
                      {v0.z, v1.z, v2.z, v3.z}, {v0.w, v1.w, v2.w, v3.w}};
#pragma unroll
    for (int ii = 0; ii < 4; ++ii) {
      int col = iw4 * 4 + ii + 1;
      uint2v pk = {cvtpk(cc[ii][0], cc[ii][1]), cvtpk(cc[ii][2], cc[ii][3])};
      *(uint2v*)&xs[(row * COLS + col) * 64 + ((chunk ^ (col & 7)) * 8) + half4] = pk;
    }
  }
  // zero-pad cols 0 and 65 (all 4 rows, all chunks)
  for (int e = tid; e < 128; e += 512) {
    int c4 = e & 15, side = (e >> 4) & 1, row = e >> 5;
    int col = side ? 65 : 0;
    int chunk = c4 >> 1, half4 = (c4 & 1) * 4;
    ushort4 z; z.x = z.y = z.z = z.w = 0;
    *(ushort4*)&xs[(row * COLS + col) * 64 + ((chunk ^ (col & 7)) * 8) + half4] = z;
  }

  // BN bias (already * log2e) -> MFMA C-in
  float Dc[4];
#pragma unroll
  for (int nt = 0; nt < 4; ++nt) Dc[nt] = g_aff[nt * 16 + b15];

  // a-frag LDS addresses (ushort idx), [mt][b][par]; padded col, no masks.
  // total row = r + prow + 1 - a; r folded into A_, (prow+1-a)*RS added per read.
  int A_[2][2][2];
#pragma unroll
  for (int mt = 0; mt < 2; ++mt)
#pragma unroll
    for (int b = 0; b < 2; ++b) {
      int col = wc * 32 + mt * 16 + b15 + (b ? p - 1 : p) + 1;  // 0..65
#pragma unroll
      for (int par = 0; par < 2; ++par)
        A_[mt][b][par] = r * ROWSTRIDE + col * 64 + (((par * 4 + q) ^ (col & 7)) * 8);
    }

  __syncthreads();  // drains wbuf[0] staging (vmcnt) + xs writes (lgkm)

  floatx4 acc[16];  // [prow*8 + mt*4 + nt], C-in = BN bias
#pragma unroll
  for (int i = 0; i < 16; ++i) {
    float d = Dc[i & 3];
    acc[i] = (floatx4){d, d, d, d};
  }

#pragma unroll
  for (int ks = 0; ks < 8; ++ks) {
    const int cur = ks & 1;
    if (ks < 7) STAGE_W(cur ^ 1, ks + 1);  // async, in flight across the MFMAs
    const int b_ = (ks >> 1) & 1, par_ = ks & 1;
    const int ro = (ks >> 2) ? 0 : ROWSTRIDE;  // (1-a)*RS
    short8 af00 = *(const short8*)&xs[A_[0][b_][par_] + ro];              // prow0 mt0
    short8 af01 = *(const short8*)&xs[A_[1][b_][par_] + ro];              // prow0 mt1
    short8 af10 = *(const short8*)&xs[A_[0][b_][par_] + ro + ROWSTRIDE];  // prow1 mt0
    short8 af11 = *(const short8*)&xs[A_[1][b_][par_] + ro + ROWSTRIDE];  // prow1 mt1
#pragma unroll
    for (int nt = 0; nt < 4; ++nt) {
      short8 bf = *(const short8*)&wbuf[((cur * 16 + c * 4 + nt) * 64 + lane) * 8];
      acc[nt]      = __builtin_amdgcn_mfma_f32_16x16x32_bf16(af00, bf, acc[nt], 0, 0, 0);
      acc[4 + nt]  = __builtin_amdgcn_mfma_f32_16x16x32_bf16(af01, bf, acc[4 + nt], 0, 0, 0);
      acc[8 + nt]  = __builtin_amdgcn_mfma_f32_16x16x32_bf16(af10, bf, acc[8 + nt], 0, 0, 0);
      acc[12 + nt] = __builtin_amdgcn_mfma_f32_16x16x32_bf16(af11, bf, acc[12 + nt], 0, 0, 0);
    }
    __syncthreads();  // stage(ks+1) complete + all reads of wbuf[cur]/xs done
  }

  // ---- xs is dead: overlay red[2][64][65] f32 on it ----
  float* red = (float*)xs;
  {
    float4 z = {0.f, 0.f, 0.f, 0.f};
    for (int e = tid; e < 2080; e += 512) ((float4*)red)[e] = z;  // 33280 B
  }
  __syncthreads();

  // ---- softmax (exp2 of pre-scaled logits) + cross-class maxpool via ds_max_u32 ----
  // (softmax outputs > 0 -> float bit pattern is order-preserving as unsigned)
#pragma unroll
  for (int prow = 0; prow < 2; ++prow)
#pragma unroll
    for (int mt = 0; mt < 2; ++mt) {
      float sm[4] = {0.f, 0.f, 0.f, 0.f};
#pragma unroll
      for (int nt = 0; nt < 4; ++nt)
#pragma unroll
        for (int reg = 0; reg < 4; ++reg) {
          float e = fexp2(acc[prow * 8 + mt * 4 + nt][reg]);
          acc[prow * 8 + mt * 4 + nt][reg] = e;
          sm[reg] += e;
        }
#pragma unroll
      for (int reg = 0; reg < 4; ++reg)
        sm[reg] = __builtin_amdgcn_rcpf(sum16(sm[reg]));
#pragma unroll
      for (int nt = 0; nt < 4; ++nt) {
        int idx = (prow * 64 + nt * 16 + b15) * 65 + wc * 32 + mt * 16 + q * 4;
#pragma unroll
        for (int reg = 0; reg < 4; ++reg) {
          float v = acc[prow * 8 + mt * 4 + nt][reg] * sm[reg];
          __hip_atomic_fetch_max((unsigned*)&red[idx + reg], __float_as_uint(v),
                                 __ATOMIC_RELAXED, __HIP_MEMORY_SCOPE_WORKGROUP);
        }
      }
    }
  __syncthreads();

  // ---- coalesced stores ----
  for (int e = tid; e < 4096; e += 512) {
    int pw2  = e & 31;
    int cout = (e >> 5) & 63;
    int rl   = e >> 11;
    int base = (rl * 64 + cout) * 65 + pw2 * 2;
    float2 val = {red[base], red[base + 1]};
    *(float2*)&out[((n * 64 + cout) * 64 + (ph0 + rl)) * 64 + pw2 * 2] = val;
  }
}

extern "C" void kernel_launch(void* const* d_in, const int* in_sizes, int n_in,
                              void* d_out, int out_size, void* d_ws, size_t ws_size,
                              hipStream_t stream) {
  const float* x     = (const float*)d_in[0];
  const float* w     = (const float*)d_in[1];
  const float* bias  = (const float*)d_in[2];
  const float* gamma = (const float*)d_in[3];
  const float* beta  = (const float*)d_in[4];
  const float* mean  = (const float*)d_in[5];
  const float* var   = (const float*)d_in[6];
  float* out = (float*)d_out;

  prep_kernel<<<8, 256, 0, stream>>>(w, bias, gamma, beta, mean, var);
  dim3 grid(32, 32);  // (pooled-row pair [XCD-swizzled], n)
  fused_kernel<<<grid, 512, 0, stream>>>(x, out);
}